// Round 1
// baseline (288.406 us; speedup 1.0000x reference)
//
#include <hip/hip_runtime.h>
#include <hip/hip_bf16.h>
#include <stdint.h>

#define NUM_MODALS 4
#define SHARED_IDX 3

typedef __attribute__((ext_vector_type(8))) short bf16x8;
typedef __attribute__((ext_vector_type(4))) float floatx4;

__device__ __forceinline__ unsigned short f2bf(float f) {
  unsigned int u = __float_as_uint(f);
  u += 0x7fffu + ((u >> 16) & 1u);   // round-to-nearest-even
  return (unsigned short)(u >> 16);
}

// W_eff[m][o][c] = Wp[o][c] + sum_r Bw[3][o][r]*A[3][r][c] + sum_r Bw[m][o][r]*A[m][r][c]
// grid: (768 o, 4 m), block: 256
__global__ void weff_kernel(const float* __restrict__ Wp,
                            const float* __restrict__ A,
                            const float* __restrict__ Bw,
                            unsigned short* __restrict__ Weff) {
  const int o = blockIdx.x;
  const int m = blockIdx.y;
  __shared__ float bsh[32];  // [0:16) shared-adapter Bw row, [16:32) modality Bw row
  const int t = threadIdx.x;
  if (t < 16)      bsh[t] = Bw[(SHARED_IDX * 768 + o) * 16 + t];
  else if (t < 32) bsh[t] = Bw[(m * 768 + o) * 16 + (t - 16)];
  __syncthreads();
  for (int c = t; c < 768; c += 256) {
    float acc = Wp[o * 768 + c];
#pragma unroll
    for (int r = 0; r < 16; ++r) {
      acc += bsh[r]      * A[(SHARED_IDX * 16 + r) * 768 + c];
      acc += bsh[16 + r] * A[(m * 16 + r) * 768 + c];
    }
    Weff[((size_t)m * 768 + o) * 768 + c] = f2bf(acc);
  }
}

// Batched GEMM: out[m] = X[m] (8192x768 fp32) * Weff[m]^T (768x768 bf16) + bp
// 128x128 output tile / block, BK=64, 4 waves each computing 64x64 (4x4 MFMA frags).
// grid: (6 col-tiles, 64 row-tiles, 4 modalities), block: 256
__global__ __launch_bounds__(256) void lora_gemm_kernel(
    const float* __restrict__ X,
    const unsigned short* __restrict__ Weff,
    const float* __restrict__ bp,
    float* __restrict__ out) {
  const int m = blockIdx.z;
  const int row_base = blockIdx.y * 128;
  const int col_base = blockIdx.x * 128;

  __shared__ alignas(16) unsigned short As[128 * 64];  // X tile, bf16
  __shared__ alignas(16) unsigned short Ws[128 * 64];  // W tile, bf16

  const int tid  = threadIdx.x;
  const int wave = tid >> 6;
  const int lane = tid & 63;
  const int ln = lane & 15;   // MFMA row/col-in-tile index
  const int qd = lane >> 4;   // MFMA quad
  const int wm = wave & 1;    // wave's 64-row slab
  const int wn = wave >> 1;   // wave's 64-col slab

  const float*          Xm = X    + (size_t)m * 8192 * 768;
  const unsigned short* Wm = Weff + (size_t)m * 768 * 768;

  floatx4 acc[4][4];
#pragma unroll
  for (int i = 0; i < 4; ++i)
#pragma unroll
    for (int j = 0; j < 4; ++j)
      acc[i][j] = (floatx4)(0.0f);

  const int xr = tid >> 4;         // base row for X staging (0..15)
  const int xc = (tid & 15) * 4;   // float4 column (0..60)

  for (int kt = 0; kt < 12; ++kt) {
    const int k0 = kt * 64;

    // ---- stage X tile: fp32 global -> bf16 LDS (128 rows x 64 cols) ----
#pragma unroll
    for (int p = 0; p < 8; ++p) {
      const int r = xr + p * 16;
      const float4 v = *(const float4*)(Xm + (size_t)(row_base + r) * 768 + k0 + xc);
      ushort4 h;
      h.x = f2bf(v.x); h.y = f2bf(v.y); h.z = f2bf(v.z); h.w = f2bf(v.w);
      *(ushort4*)(&As[r * 64 + xc]) = h;
    }

    // ---- stage W tile via global_load_lds, 16B/lane (1 KiB = 8 rows per issue) ----
#pragma unroll
    for (int p = 0; p < 4; ++p) {
      const int o_local = wave * 32 + p * 8 + (lane >> 3);
      const int kc = (lane & 7) * 8;
      const unsigned short* src = Wm + (size_t)(col_base + o_local) * 768 + k0 + kc;
      __builtin_amdgcn_global_load_lds(
          (const __attribute__((address_space(1))) void*)src,
          (__attribute__((address_space(3))) void*)&Ws[(wave * 32 + p * 8) * 64],
          16, 0, 0);
    }
    __syncthreads();

    // ---- MFMA over BK=64 (two k=32 steps) ----
#pragma unroll
    for (int kk = 0; kk < 64; kk += 32) {
      bf16x8 a[4], b[4];
#pragma unroll
      for (int i = 0; i < 4; ++i)
        a[i] = *(const bf16x8*)(&As[(wm * 64 + i * 16 + ln) * 64 + kk + qd * 8]);
#pragma unroll
      for (int j = 0; j < 4; ++j)
        b[j] = *(const bf16x8*)(&Ws[(wn * 64 + j * 16 + ln) * 64 + kk + qd * 8]);
#pragma unroll
      for (int i = 0; i < 4; ++i)
#pragma unroll
        for (int j = 0; j < 4; ++j)
          acc[i][j] = __builtin_amdgcn_mfma_f32_16x16x32_bf16(a[i], b[j], acc[i][j], 0, 0, 0);
    }
    __syncthreads();
  }

  // ---- epilogue: + bias, fp32 store ----
  float* Om = out + (size_t)m * 8192 * 768;
#pragma unroll
  for (int j = 0; j < 4; ++j) {
    const int o = col_base + wn * 64 + j * 16 + ln;
    const float bias = bp[o];
#pragma unroll
    for (int i = 0; i < 4; ++i) {
      const int R = row_base + wm * 64 + i * 16 + qd * 4;
      float* dst = Om + (size_t)R * 768 + o;
#pragma unroll
      for (int v = 0; v < 4; ++v)
        dst[(size_t)v * 768] = acc[i][j][v] + bias;
    }
  }
}

extern "C" void kernel_launch(void* const* d_in, const int* in_sizes, int n_in,
                              void* d_out, int out_size, void* d_ws, size_t ws_size,
                              hipStream_t stream) {
  const float* x  = (const float*)d_in[0];   // [32, 1024, 768]
  const float* Wp = (const float*)d_in[1];   // [768, 768]
  const float* bp = (const float*)d_in[2];   // [768]
  const float* A  = (const float*)d_in[3];   // [4, 16, 768]
  const float* Bw = (const float*)d_in[4];   // [4, 768, 16]
  float* out = (float*)d_out;                // [32, 1024, 768]

  unsigned short* Weff = (unsigned short*)d_ws;  // [4][768][768] bf16 = 4.5 MB

  weff_kernel<<<dim3(768, 4), 256, 0, stream>>>(Wp, A, Bw, Weff);
  lora_gemm_kernel<<<dim3(6, 64, 4), 256, 0, stream>>>(x, Weff, bp, out);
}